// Round 18
// baseline (348.927 us; speedup 1.0000x reference)
//
#include <hip/hip_runtime.h>
#include <hip/hip_bf16.h>
#include <math.h>

// Problem constants (from reference)
constexpr int NTOT = 4608;   // N_NODES
constexpr int TC   = 3072;   // TOTAL_CATS
constexpr int MU   = 1536;   // MAX_UNIFY
constexpr int NH   = 4;      // heads

// ---------------- workspace layout (float offsets) ----------------
constexpr long OFF_ADJ  = 0;                                  // N*N sim region (partially used)
constexpr long OFF_X1   = OFF_ADJ  + (long)NTOT*NTOT;         // N*256 (pre-relu)
constexpr long OFF_NAF  = OFF_X1   + (long)NTOT*256;          // naf_T [64][NTOT]
constexpr long OFF_PART = OFF_NAF  + (long)NTOT*64;           // (unused)
constexpr long OFF_RINV = OFF_PART + 72*64;                   // N
constexpr long OFF_WH   = OFF_RINV + NTOT;                    // 4*N*64
constexpr long OFF_F1H  = OFF_WH   + (long)4*NTOT*64;         // 4*N
constexpr long OFF_F2H  = OFF_F1H  + (long)4*NTOT;
constexpr long OFF_MXH  = OFF_F2H  + (long)4*NTOT;            // (unused)
constexpr long OFF_CIH  = OFF_MXH  + (long)4*NTOT;            // (unused)
constexpr long OFF_X2   = OFF_CIH  + (long)4*NTOT;            // N*256
constexpr long OFF_WH2  = OFF_X2   + (long)NTOT*256;          // N*256 (acc1 before Wh2 exists)
constexpr long OFF_F1S  = OFF_WH2  + (long)NTOT*256;          // N
constexpr long OFF_F2S  = OFF_F1S  + NTOT;
constexpr long OFF_MXS  = OFF_F2S  + NTOT;                    // (unused)
constexpr long OFF_CIS  = OFF_MXS  + NTOT;                    // (unused)
constexpr long OFF_X3   = OFF_CIS  + NTOT;                    // 1536*256
constexpr long OFF_PMAX = OFF_X3   + (long)MU*256;            // (unused now; bi partials in scratch)
constexpr long OFF_PSUM = OFF_PMAX + (long)2*12*MU;
constexpr long OFF_FMAX = OFF_PSUM + (long)2*12*MU;           // 2*1536
constexpr long OFF_FIS  = OFF_FMAX + (long)2*MU;
constexpr long OFF_L1   = OFF_FIS  + (long)2*MU;              // 4*N unnormalized row sums (mh)
constexpr long OFF_L2   = OFF_L1   + (long)4*NTOT;            // MU row sums (s)
// sim region: values stored ONLY for rows<TC, cols>=TC. Rows>=TC carved as scratch:
constexpr long OFF_PARTS = OFF_ADJ + (long)TC*NTOT;           // double[NTOT][36] row-sum partials (128-col granule)
constexpr long OFF_POSB  = OFF_PARTS + 2L*NTOT*36;            // u64[NTOT][72] sign words
constexpr long OFF_MASKB = OFF_POSB  + 2L*NTOT*72;            // u64[72][NTOT] mask words (TRANSPOSED)
constexpr long OFF_PM2   = OFF_MASKB + 2L*NTOT*72;            // float[2][96][MU] bi chunk max
constexpr long OFF_PS2   = OFF_PM2   + 2L*96*MU;              // float[2][96][MU] bi chunk sum
// Aliases (lifetime-checked):
//   acc1  = OFF_WH2 region (dead until Wh2 gemm, after mh_fin)
//   Whbf  = OFF_X2 region as bf16 [4][64][NTOT] (x2 written only by mh_fin)
//   acc2  = OFF_X1 (x1p dead after mh_fin; mh_fin itself zeroes it); Wh2bf = OFF_X1 + MU*256 as bf16
// Numerics constraints (rounds 1-5 post-mortems):
//   - rinv MUST be the fp64 sum of the fp32-ROUNDED sim values (exact naf.S fails at 0.154;
//     bf16-MFMA values fail at 0.16-0.40). Full matrix stays fp32 FMA, r0 per-element K-order.
//   - fp64 partial GRANULARITY is free (association at ~1e-16): parts at 128-col granule.
// Perf record: r13 attn composite 46.2 KEEP | r14 bi chunks: 344.6 | r17 restore: 343.2 BEST.
//   r15 sim A-from-global REGRESSED (broadcast reads were free). r16 sim 512-thread REGRESSED
//   (VGPR capped at 40 -> spill; 512-thread needs launch_bounds 2nd arg).
// r18: sim_k8 BK 32->16. LDS 36.9 -> 20.5 KB => 7 blocks/CU = 28 waves/CU (was 16; VGPR=64
//   allows 32). 256-thread blocks (no spill trap), LDS broadcast retained, per-thread kk order
//   still sequential 0..63 -> bit-identical values. Cost: 8 barriers vs 4.

typedef __attribute__((ext_vector_type(8))) short bf16x8;
typedef __attribute__((ext_vector_type(8))) unsigned short ushort8;
typedef __attribute__((ext_vector_type(4))) float floatx4;

__device__ __forceinline__ float elu(float x)   { return (x > 0.f) ? x : expm1f(x); }
__device__ __forceinline__ unsigned short f2bf(float f) {
    unsigned u = __float_as_uint(f);
    u += 0x7FFFu + ((u >> 16) & 1u);           // round-to-nearest-even
    return (unsigned short)(u >> 16);
}

// ---------------- zero-fill two regions (float4 units) ----------------
__global__ __launch_bounds__(256) void zero2_k(
    float* __restrict__ a, long na4, float* __restrict__ b, long nb4)
{
    long i = (long)blockIdx.x * 256 + threadIdx.x;
    float4 z = make_float4(0.f, 0.f, 0.f, 0.f);
    if (i < na4) *(float4*)(a + i * 4) = z;
    else {
        long j = i - na4;
        if (j < nb4) *(float4*)(b + j * 4) = z;
    }
}

// ---------------- generic tiled fp32 GEMM: C = A(NxK) @ B(KxM) [+bias] ----------------
template<bool RELU_A, bool BIAS>
__global__ __launch_bounds__(256) void gemm_rm(
    const float* __restrict__ A, const float* __restrict__ B,
    const float* __restrict__ bias, float* __restrict__ C,
    int K, int M, long strideBz, long strideCz)
{
    __shared__ float As[16][68];
    __shared__ float Bs[16][68];
    const float* Bz = B + (long)blockIdx.z * strideBz;
    float* Cz = C + (long)blockIdx.z * strideCz;
    int tid = threadIdx.x;
    int r0 = blockIdx.x * 64;
    int c0 = blockIdx.y * 64;
    int ty = tid >> 4, tx = tid & 15;
    int srow = tid >> 2, skg = tid & 3;     // A staging role
    int bkk = tid >> 4, bc4 = (tid & 15) * 4;  // B staging role (float4)
    const float* Arow = A + (long)(r0 + srow) * K + skg * 4;
    float4 aReg = *(const float4*)(Arow);
    float4 bReg = *(const float4*)&Bz[(long)bkk * M + c0 + bc4];
    float acc[4][4] = {};
    for (int k0 = 0; k0 < K; k0 += 16) {
        {
            float4 v = aReg;
            if (RELU_A) {
                v.x = fmaxf(v.x, 0.f); v.y = fmaxf(v.y, 0.f);
                v.z = fmaxf(v.z, 0.f); v.w = fmaxf(v.w, 0.f);
            }
            As[skg * 4 + 0][srow] = v.x;
            As[skg * 4 + 1][srow] = v.y;
            As[skg * 4 + 2][srow] = v.z;
            As[skg * 4 + 3][srow] = v.w;
            *(float4*)&Bs[bkk][bc4] = bReg;
        }
        __syncthreads();
        if (k0 + 16 < K) {   // prefetch next tile; latency hides under the FMA loop
            aReg = *(const float4*)(Arow + k0 + 16);
            bReg = *(const float4*)&Bz[(long)(k0 + 16 + bkk) * M + c0 + bc4];
        }
        #pragma unroll
        for (int kk = 0; kk < 16; ++kk) {
            float4 av = *(const float4*)&As[kk][ty * 4];
            float4 bv = *(const float4*)&Bs[kk][tx * 4];
            float a[4] = { av.x, av.y, av.z, av.w };
            float b[4] = { bv.x, bv.y, bv.z, bv.w };
            #pragma unroll
            for (int i = 0; i < 4; ++i)
                #pragma unroll
                for (int j = 0; j < 4; ++j) acc[i][j] += a[i] * b[j];
        }
        __syncthreads();
    }
    #pragma unroll
    for (int i = 0; i < 4; ++i) {
        int r = r0 + ty * 4 + i;
        #pragma unroll
        for (int j = 0; j < 4; ++j) {
            int c = c0 + tx * 4 + j;
            float v = acc[i][j];
            if (BIAS) v += bias[c];
            Cz[(long)r * M + c] = v;
        }
    }
}

// ---------------- af = x1 @ W_adj + b_adj; naf_T[k][n] = af/||af|| (transposed) ----------------
__global__ __launch_bounds__(256) void af_naf(
    const float* __restrict__ x1, const float* __restrict__ W_adj,
    const float* __restrict__ b_adj, float* __restrict__ nafT)
{
    __shared__ float rowbuf[4][256];
    int tid = threadIdx.x, w = tid >> 6, lane = tid & 63;
    int n = blockIdx.x * 4 + w;
    #pragma unroll
    for (int l = 0; l < 4; ++l) rowbuf[w][l * 64 + lane] = x1[(long)n * 256 + l * 64 + lane];
    __syncthreads();
    float acc = b_adj[lane];
    for (int k = 0; k < 256; ++k) acc += rowbuf[w][k] * W_adj[k * 64 + lane];
    float sq = acc * acc;
    #pragma unroll
    for (int off = 32; off >= 1; off >>= 1) sq += __shfl_xor(sq, off);
    float nrm = fmaxf(sqrtf(sq), 1e-12f);
    nafT[(long)lane * NTOT + n] = acc / nrm;
}

// ---------------- sim 128x128 tile, 8x8/thread, BK=16 (20.5 KB LDS -> 7 blocks/CU) ----------------
// Per-thread kk order still sequential 0..63 -> bit-identical values vs r17.
__global__ __launch_bounds__(256) void sim_k8(
    const float* __restrict__ nafT, float* __restrict__ sim,
    double* __restrict__ parts, unsigned long long* __restrict__ posb)
{
    __shared__ float As[16][128];
    __shared__ float Bs[16][128];
    __shared__ unsigned char sgn[128][2][16];
    int tid = threadIdx.x;
    int n0 = blockIdx.x * 128, m0 = blockIdx.y * 128;
    int ty = tid >> 4, tx = tid & 15;
    float acc[2][2][4][4] = {};   // [row-half][col-half][i][j]
    for (int ks = 0; ks < 4; ++ks) {
        if (ks) __syncthreads();
        int k0 = ks * 16;
        #pragma unroll
        for (int l = 0; l < 2; ++l) {
            int idx = l * 256 + tid;
            int kk = idx >> 5, f4 = idx & 31;
            *(float4*)&As[kk][f4 * 4] = *(const float4*)&nafT[(long)(k0 + kk) * NTOT + n0 + f4 * 4];
            *(float4*)&Bs[kk][f4 * 4] = *(const float4*)&nafT[(long)(k0 + kk) * NTOT + m0 + f4 * 4];
        }
        __syncthreads();
        for (int kk = 0; kk < 16; ++kk) {
            float4 av0 = *(const float4*)&As[kk][ty * 4];
            float4 av1 = *(const float4*)&As[kk][64 + ty * 4];
            float4 bv0 = *(const float4*)&Bs[kk][tx * 4];
            float4 bv1 = *(const float4*)&Bs[kk][64 + tx * 4];
            float a[2][4] = { { av0.x, av0.y, av0.z, av0.w }, { av1.x, av1.y, av1.z, av1.w } };
            float b[2][4] = { { bv0.x, bv0.y, bv0.z, bv0.w }, { bv1.x, bv1.y, bv1.z, bv1.w } };
            #pragma unroll
            for (int rh = 0; rh < 2; ++rh)
                #pragma unroll
                for (int ch = 0; ch < 2; ++ch)
                    #pragma unroll
                    for (int i = 0; i < 4; ++i)
                        #pragma unroll
                        for (int j = 0; j < 4; ++j)
                            acc[rh][ch][i][j] += a[rh][i] * b[ch][j];
        }
    }
    // (1) values only for the bi-softmax slice (rows<TC, cols>=TC)
    if (m0 >= TC && n0 < TC) {
        #pragma unroll
        for (int rh = 0; rh < 2; ++rh)
            #pragma unroll
            for (int i = 0; i < 4; ++i) {
                long r = n0 + rh * 64 + ty * 4 + i;
                #pragma unroll
                for (int ch = 0; ch < 2; ++ch) {
                    float4 o = make_float4(acc[rh][ch][i][0], acc[rh][ch][i][1],
                                           acc[rh][ch][i][2], acc[rh][ch][i][3]);
                    *(float4*)(sim + r * NTOT + m0 + ch * 64 + tx * 4) = o;
                }
            }
    }
    // (2) fp64 per-row partial over the FULL 128-col tile (one butterfly per row)
    int mt36 = m0 >> 7;
    #pragma unroll
    for (int rh = 0; rh < 2; ++rh)
        #pragma unroll
        for (int i = 0; i < 4; ++i) {
            double t = 0.0;
            #pragma unroll
            for (int ch = 0; ch < 2; ++ch)
                t += ((double)acc[rh][ch][i][0] + (double)acc[rh][ch][i][1])
                   + ((double)acc[rh][ch][i][2] + (double)acc[rh][ch][i][3]);
            #pragma unroll
            for (int off = 1; off < 16; off <<= 1) t += __shfl_xor(t, off);
            if (tx == 0)
                parts[(long)(n0 + rh * 64 + ty * 4 + i) * 36 + mt36] = t;
        }
    // (3) sign nibbles -> u64 words (bit = local col within 64-col granule)
    int mt = m0 >> 6;
    #pragma unroll
    for (int rh = 0; rh < 2; ++rh)
        #pragma unroll
        for (int i = 0; i < 4; ++i)
            #pragma unroll
            for (int ch = 0; ch < 2; ++ch) {
                unsigned nib = (unsigned)(acc[rh][ch][i][0] > 0.f)
                             | ((unsigned)(acc[rh][ch][i][1] > 0.f) << 1)
                             | ((unsigned)(acc[rh][ch][i][2] > 0.f) << 2)
                             | ((unsigned)(acc[rh][ch][i][3] > 0.f) << 3);
                sgn[rh * 64 + ty * 4 + i][ch][tx] = (unsigned char)nib;
            }
    __syncthreads();
    {
        int rl = tid >> 1, gh = tid & 1;
        unsigned long long w = 0;
        #pragma unroll
        for (int t = 0; t < 16; ++t)
            w |= (unsigned long long)sgn[rl][gh][t] << (4 * t);
        posb[(long)(n0 + rl) * 72 + mt + gh] = w;
    }
}

// ---------------- fused1: cvt_t(Wh heads -> Whbf[4][64][NTOT]) + dots_k(heads) + rowfin ----------------
// maskT layout: maskT[mt * NTOT + n]
__global__ __launch_bounds__(256) void fused1(
    const float* __restrict__ Wh, unsigned short* __restrict__ Whbf,
    const float* __restrict__ a_heads,
    float* __restrict__ f1, float* __restrict__ f2,
    const double* __restrict__ parts, const unsigned long long* __restrict__ posb,
    float* __restrict__ rinv, unsigned long long* __restrict__ maskT)
{
    __shared__ float t[64][65];
    int b = blockIdx.x;
    int tid = threadIdx.x;
    if (b < 288) {
        // cvt_t: in [4][NTOT][64] fp32 -> out [4][64][NTOT] bf16
        int bx = b % 72, bz = b / 72;
        int n0 = bx * 64;
        const float* inz = Wh + (long)bz * NTOT * 64;
        unsigned short* outz = Whbf + (long)bz * 64 * NTOT;
        int r4 = tid >> 6, k = tid & 63;
        #pragma unroll
        for (int l = 0; l < 16; ++l) {
            int row = l * 4 + r4;
            t[row][k] = inz[(long)(n0 + row) * 64 + k];
        }
        __syncthreads();
        #pragma unroll
        for (int l = 0; l < 16; ++l) {
            int drow = l * 4 + r4;
            outz[(long)drow * NTOT + n0 + k] = f2bf(t[k][drow]);
        }
    } else if (b < 288 + 4608) {
        // dots_k heads (D=64)
        int tb = b - 288;
        int xb = tb % 1152, h = tb / 1152;
        int w = tid >> 6, lane = tid & 63;
        int n = xb * 4 + w;
        const float* row = Wh + ((long)h * NTOT + n) * 64;
        const float* a1 = a_heads + (long)h * 128;
        const float* a2 = a1 + 64;
        float v = row[lane];
        float p1 = v * a1[lane];
        float p2 = v * a2[lane];
        #pragma unroll
        for (int off = 32; off >= 1; off >>= 1) { p1 += __shfl_xor(p1, off); p2 += __shfl_xor(p2, off); }
        if (lane == 0) {
            f1[(long)h * NTOT + n] = p1;
            f2[(long)h * NTOT + n] = p2;
        }
    } else {
        // rowfin: combine 36 fp64 partials -> rinv; sign words -> TRANSPOSED mask words
        int xb = b - (288 + 4608);
        int w = tid >> 6, lane = tid & 63;
        int n = xb * 4 + w;
        double s = (lane < 36) ? parts[(long)n * 36 + lane] : 0.0;
        #pragma unroll
        for (int off = 32; off >= 1; off >>= 1) s += __shfl_xor(s, off);
        float rs = (float)s;
        float r = 1.0f / rs;
        if (isinf(r)) r = 0.f;
        if (lane == 0) rinv[n] = r;
        unsigned long long pw = posb[(long)n * 72 + lane];
        unsigned long long mw = (r < 0.f) ? ~pw : pw;
        if (r == 0.f) mw = 0ull;
        maskT[(long)lane * NTOT + n] = mw;
        if (lane < 8) {
            pw = posb[(long)n * 72 + 64 + lane];
            mw = (r < 0.f) ? ~pw : pw;
            if (r == 0.f) mw = 0ull;
            maskT[(long)(64 + lane) * NTOT + n] = mw;
        }
    }
}

// ---------------- fused2: cvt_t(Wh2 -> Wh2bf[256][NTOT]) + dots_k(single, D=256) ----------------
__global__ __launch_bounds__(256) void fused2(
    const float* __restrict__ Wh2, unsigned short* __restrict__ Wh2bf,
    const float* __restrict__ a_out,
    float* __restrict__ f1, float* __restrict__ f2)
{
    __shared__ float t[64][65];
    int b = blockIdx.x;
    int tid = threadIdx.x;
    if (b < 288) {
        int bx = b % 72, by = b / 72;
        int n0 = bx * 64, d0 = by * 64;
        int r4 = tid >> 6, k = tid & 63;
        #pragma unroll
        for (int l = 0; l < 16; ++l) {
            int row = l * 4 + r4;
            t[row][k] = Wh2[(long)(n0 + row) * 256 + d0 + k];
        }
        __syncthreads();
        #pragma unroll
        for (int l = 0; l < 16; ++l) {
            int drow = l * 4 + r4;
            Wh2bf[(long)(d0 + drow) * NTOT + n0 + k] = f2bf(t[k][drow]);
        }
    } else {
        int xb = b - 288;
        int w = tid >> 6, lane = tid & 63;
        int n = xb * 4 + w;
        const float* row = Wh2 + (long)n * 256;
        const float* a1 = a_out;
        const float* a2 = a_out + 256;
        float p1 = 0.f, p2 = 0.f;
        #pragma unroll
        for (int l = 0; l < 4; ++l) {
            float v = row[l * 64 + lane];
            p1 += v * a1[l * 64 + lane];
            p2 += v * a2[l * 64 + lane];
        }
        #pragma unroll
        for (int off = 32; off >= 1; off >>= 1) { p1 += __shfl_xor(p1, off); p2 += __shfl_xor(p2, off); }
        if (lane == 0) {
            f1[n] = p1;
            f2[n] = p2;
        }
    }
}

// ---------------- multihead att @ Wh — LDS stride 72, inline exp, register-pipelined staging ----------------
__global__ __launch_bounds__(256) void mh_attn(
    const unsigned long long* __restrict__ maskT,
    const float* __restrict__ f1, const float* __restrict__ f2,
    const unsigned short* __restrict__ Whbf, float* __restrict__ accb,
    float* __restrict__ lbuf)
{
    __shared__ unsigned short Ws[2][64][72];   // Wh tile transposed [d][m] bf16
    int tid = threadIdx.x;
    int wave = tid >> 6, lane = tid & 63;
    int n0 = blockIdx.x * 64;
    int h = blockIdx.y, ch = blockIdx.z;
    const float* f2h = f2 + (long)h * NTOT;
    const unsigned short* Wb = Whbf + (long)h * 64 * NTOT;
    int wd = tid >> 2, wc = (tid & 3) * 16;
    int arow = lane & 15, acol8 = (lane >> 4) * 8;
    int n = n0 + 16 * wave + arow;
    float r1 = f1[(long)h * NTOT + n];
    float lsum = 0.f;
    floatx4 acc[4] = {};
    int buf = 0;
    int mt0 = ch * 12;
    // preload iteration 0 staging + mask
    ushort8 wv0 = *(const ushort8*)&Wb[(long)wd * NTOT + mt0 * 64 + wc];
    ushort8 wv1 = *(const ushort8*)&Wb[(long)wd * NTOT + mt0 * 64 + wc + 8];
    unsigned long long mw = maskT[(long)mt0 * NTOT + n];
    for (int i = 0; i < 12; ++i) {
        int m0 = (mt0 + i) * 64;
        // P-gen: f2 table loads inline (L1-hot) + inline exp (VALU covers staging latency)
        bf16x8 afr[2];
        #pragma unroll
        for (int ks = 0; ks < 2; ++ks) {
            int mc = m0 + ks * 32 + acol8;
            float4 fv0 = *(const float4*)(f2h + mc);
            float4 fv1 = *(const float4*)(f2h + mc + 4);
            unsigned bits = (unsigned)(mw >> (ks * 32 + acol8)) & 0xFFu;
            float f[8] = { fv0.x, fv0.y, fv0.z, fv0.w, fv1.x, fv1.y, fv1.z, fv1.w };
            #pragma unroll
            for (int j = 0; j < 8; ++j) {
                float s = r1 + f[j];
                float e = __expf(fmaxf(s, 0.2f * s));
                float p = ((bits >> j) & 1u) ? e : 0.f;
                lsum += p;
                afr[ks][j] = (short)f2bf(p);
            }
        }
        *(ushort8*)&Ws[buf][wd][wc] = wv0;
        *(ushort8*)&Ws[buf][wd][wc + 8] = wv1;
        // prefetch iteration i+1 staging + mask (latency hides under barrier + MFMA)
        if (i < 11) {
            int m1 = (mt0 + i + 1) * 64;
            wv0 = *(const ushort8*)&Wb[(long)wd * NTOT + m1 + wc];
            wv1 = *(const ushort8*)&Wb[(long)wd * NTOT + m1 + wc + 8];
            mw = maskT[(long)(mt0 + i + 1) * NTOT + n];
        }
        __syncthreads();
        #pragma unroll
        for (int ks = 0; ks < 2; ++ks) {
            #pragma unroll
            for (int dt = 0; dt < 4; ++dt) {
                bf16x8 bfr = *(bf16x8*)&Ws[buf][16 * dt + arow][ks * 32 + acol8];
                acc[dt] = __builtin_amdgcn_mfma_f32_16x16x32_bf16(afr[ks], bfr, acc[dt], 0, 0, 0);
            }
        }
        buf ^= 1;
    }
    lsum += __shfl_xor(lsum, 16);
    lsum += __shfl_xor(lsum, 32);
    if (lane < 16) atomicAdd(lbuf + (long)h * NTOT + n0 + 16 * wave + lane, lsum);
    int crow = n0 + 16 * wave + (lane >> 4) * 4;
    int ccol = h * 64 + (lane & 15);
    #pragma unroll
    for (int dt = 0; dt < 4; ++dt)
        #pragma unroll
        for (int r = 0; r < 4; ++r)
            atomicAdd(accb + (long)(crow + r) * 256 + ccol + dt * 16, acc[dt][r]);
}

// ---------------- mh epilogue: x2 = elu(acc / l') + relu(x1); also zeroes acc2 region ----------------
__global__ __launch_bounds__(256) void mh_fin(
    const float* __restrict__ accb, const float* __restrict__ lbuf,
    float* __restrict__ x1, float* __restrict__ x2)
{
    long idx = ((long)blockIdx.x * 256 + threadIdx.x) * 4;
    long r = idx >> 8;
    int h = (int)((idx & 255) >> 6);
    float l = lbuf[(long)h * NTOT + r];
    float inv = (l > 0.f) ? 1.0f / l : 0.f;
    float4 a = *(const float4*)(accb + idx);
    float4 xv = *(const float4*)(x1 + idx);
    float4 o;
    o.x = elu(a.x * inv) + fmaxf(xv.x, 0.f);
    o.y = elu(a.y * inv) + fmaxf(xv.y, 0.f);
    o.z = elu(a.z * inv) + fmaxf(xv.z, 0.f);
    o.w = elu(a.w * inv) + fmaxf(xv.w, 0.f);
    *(float4*)(x2 + idx) = o;
    // pre-zero acc2 (aliases head of x1p region, which is dead after this read)
    if (idx < (long)MU * 256)
        *(float4*)(x1 + idx) = make_float4(0.f, 0.f, 0.f, 0.f);
}

// ---------------- single-head att @ Wh2 (rows >= TC) — LDS stride 72, inline exp, pipelined ----------------
__global__ __launch_bounds__(256) void s_attn(
    const unsigned long long* __restrict__ maskT,
    const float* __restrict__ f1, const float* __restrict__ f2,
    const unsigned short* __restrict__ Wh2bf, float* __restrict__ accb,
    float* __restrict__ lbuf)
{
    __shared__ unsigned short Ws[2][128][72];   // 36.9 KB: 128 d-rows x 64 m, dbuf
    int tid = threadIdx.x;
    int wave = tid >> 6, lane = tid & 63;
    int lr0 = blockIdx.x * 32;
    int c0 = blockIdx.y * 128;
    int ch = blockIdx.z;
    int wdl = tid >> 2, wc = (tid & 3) * 16;    // staging role (applied twice for 128 rows)
    int arow = lane & 15, acol8 = (lane >> 4) * 8;
    int rt = wave & 1;
    int dt0 = (wave >> 1) * 4;                   // 4 d-tiles of 16 per wave
    int n = TC + lr0 + 16 * rt + arow;
    float r1 = f1[n];
    float lsum = 0.f;
    floatx4 acc[4] = {};
    int buf = 0;
    int mt0 = ch * 6;
    // preload iteration 0 staging + mask
    ushort8 wva0 = *(const ushort8*)&Wh2bf[(long)(c0 + wdl) * NTOT + mt0 * 64 + wc];
    ushort8 wva1 = *(const ushort8*)&Wh2bf[(long)(c0 + wdl) * NTOT + mt0 * 64 + wc + 8];
    ushort8 wvb0 = *(const ushort8*)&Wh2bf[(long)(c0 + 64 + wdl) * NTOT + mt0 * 64 + wc];
    ushort8 wvb1 = *(const ushort8*)&Wh2bf[(long)(c0 + 64 + wdl) * NTOT + mt0 * 64 + wc + 8];
    unsigned long long mw = maskT[(long)mt0 * NTOT + n];
    for (int i = 0; i < 6; ++i) {
        int m0 = (mt0 + i) * 64;
        bf16x8 afr[2];
        #pragma unroll
        for (int ks = 0; ks < 2; ++ks) {
            int mc = m0 + ks * 32 + acol8;
            float4 fv0 = *(const float4*)(f2 + mc);
            float4 fv1 = *(const float4*)(f2 + mc + 4);
            unsigned bits = (unsigned)(mw >> (ks * 32 + acol8)) & 0xFFu;
            float f[8] = { fv0.x, fv0.y, fv0.z, fv0.w, fv1.x, fv1.y, fv1.z, fv1.w };
            #pragma unroll
            for (int j = 0; j < 8; ++j) {
                float s = r1 + f[j];
                float e = __expf(fmaxf(s, 0.2f * s));
                float p = ((bits >> j) & 1u) ? e : 0.f;
                lsum += p;
                afr[ks][j] = (short)f2bf(p);
            }
        }
        *(ushort8*)&Ws[buf][wdl][wc] = wva0;
        *(ushort8*)&Ws[buf][wdl][wc + 8] = wva1;
        *(ushort8*)&Ws[buf][64 + wdl][wc] = wvb0;
        *(ushort8*)&Ws[buf][64 + wdl][wc + 8] = wvb1;
        if (i < 5) {
            int m1 = (mt0 + i + 1) * 64;
            wva0 = *(const ushort8*)&Wh2bf[(long)(c0 + wdl) * NTOT + m1 + wc];
            wva1 = *(const ushort8*)&Wh2bf[(long)(c0 + wdl) * NTOT + m1 + wc + 8];
            wvb0 = *(const ushort8*)&Wh2bf[(long)(c0 + 64 + wdl) * NTOT + m1 + wc];
            wvb1 = *(const ushort8*)&Wh2bf[(long)(c0 + 64 + wdl) * NTOT + m1 + wc + 8];
            mw = maskT[(long)(mt0 + i + 1) * NTOT + n];
        }
        __syncthreads();
        #pragma unroll
        for (int ks = 0; ks < 2; ++ks) {
            #pragma unroll
            for (int t = 0; t < 4; ++t) {
                bf16x8 bfr = *(bf16x8*)&Ws[buf][(dt0 + t) * 16 + arow][ks * 32 + acol8];
                acc[t] = __builtin_amdgcn_mfma_f32_16x16x32_bf16(afr[ks], bfr, acc[t], 0, 0, 0);
            }
        }
        buf ^= 1;
    }
    // per-row l': contribute once (col-half 0, waves 0,1 only)
    lsum += __shfl_xor(lsum, 16);
    lsum += __shfl_xor(lsum, 32);
    if (blockIdx.y == 0 && wave < 2 && lane < 16)
        atomicAdd(lbuf + lr0 + 16 * wave + lane, lsum);
    int crow = lr0 + 16 * rt + (lane >> 4) * 4;
    #pragma unroll
    for (int t = 0; t < 4; ++t) {
        int ccol = c0 + (dt0 + t) * 16 + (lane & 15);
        #pragma unroll
        for (int r = 0; r < 4; ++r)
            atomicAdd(accb + (long)(crow + r) * 256 + ccol, acc[t][r]);
    }
}

// ---------------- s epilogue: x3 = elu(acc / l' + x2[TC..]) ----------------
__global__ __launch_bounds__(256) void s_fin(
    const float* __restrict__ accb, const float* __restrict__ lbuf,
    const float* __restrict__ x2, float* __restrict__ x3)
{
    long idx = ((long)blockIdx.x * 256 + threadIdx.x) * 4;
    long r = idx >> 8;
    float l = lbuf[r];
    float inv = (l > 0.f) ? 1.0f / l : 0.f;
    float4 a = *(const float4*)(accb + idx);
    float4 xv = *(const float4*)(x2 + (long)TC * 256 + idx);
    float4 o;
    o.x = elu(a.x * inv + xv.x);
    o.y = elu(a.y * inv + xv.y);
    o.z = elu(a.z * inv + xv.z);
    o.w = elu(a.w * inv + xv.w);
    *(float4*)(x3 + idx) = o;
}

// ---------------- bi-softmax phase A: 16-row chunks (96 per dataset) ----------------
__global__ __launch_bounds__(256) void bi_partial(
    const float* __restrict__ sim, const float* __restrict__ rinv,
    float* __restrict__ pmax, float* __restrict__ psum)
{
    int c = blockIdx.x * 256 + threadIdx.x;
    int ch = blockIdx.y;                       // 0..95
    int ds = blockIdx.z;
    float m = -3.0e38f, s = 0.f;
    int rbase = ds * MU + ch * 16;
    for (int r = 0; r < 16; ++r) {
        float a = sim[(long)(rbase + r) * NTOT + TC + c] * rinv[rbase + r];
        float v = a * 20.0f;
        if (v <= m) s += expf(v - m);
        else { s = s * expf(m - v) + 1.f; m = v; }
    }
    pmax[((long)ds * 96 + ch) * MU + c] = m;
    psum[((long)ds * 96 + ch) * MU + c] = s;
}

// ---------------- bi-softmax phase B: fold 96 chunk partials ----------------
__global__ __launch_bounds__(256) void bi_combine(
    const float* __restrict__ pmax, const float* __restrict__ psum,
    float* __restrict__ fmax, float* __restrict__ fis)
{
    int b = blockIdx.x;
    int ds = b / 6, ct = b % 6;
    int c = ct * 256 + threadIdx.x;
    float m = -3.0e38f;
    for (int ch = 0; ch < 96; ++ch) m = fmaxf(m, pmax[((long)ds * 96 + ch) * MU + c]);
    float s = 0.f;
    for (int ch = 0; ch < 96; ++ch)
        s += psum[((long)ds * 96 + ch) * MU + c] * expf(pmax[((long)ds * 96 + ch) * MU + c] - m);
    fmax[ds * MU + c] = m;
    fis[ds * MU + c] = 1.0f / s;
}

// ---------------- bi-softmax phase C: 16-row chunks ----------------
__global__ __launch_bounds__(256) void bi_norm(
    const float* __restrict__ sim, const float* __restrict__ rinv,
    const float* __restrict__ fmax, const float* __restrict__ fis,
    float* __restrict__ outbg)
{
    int c = blockIdx.x * 256 + threadIdx.x;
    int ch = blockIdx.y;                       // 0..95
    int ds = blockIdx.z;
    float m = fmax[ds * MU + c], inv = fis[ds * MU + c];
    long obase = (long)ds * MU * MU;
    int rbase = ch * 16;
    for (int r = 0; r < 16; ++r) {
        int row = ds * MU + rbase + r;
        float a = sim[(long)row * NTOT + TC + c] * rinv[row];
        float v = a * 20.0f;
        outbg[obase + (long)(rbase + r) * MU + c] = expf(v - m) * inv;
    }
}

// ---------------- launch ----------------
extern "C" void kernel_launch(void* const* d_in, const int* in_sizes, int n_in,
                              void* d_out, int out_size, void* d_ws, size_t ws_size,
                              hipStream_t stream)
{
    const float* x        = (const float*)d_in[0];
    const float* W_before = (const float*)d_in[1];
    const float* b_before = (const float*)d_in[2];
    const float* W_adj    = (const float*)d_in[3];
    const float* b_adj    = (const float*)d_in[4];
    const float* W_heads  = (const float*)d_in[5];
    const float* a_heads  = (const float*)d_in[6];
    const float* W_out    = (const float*)d_in[7];
    const float* a_out    = (const float*)d_in[8];
    const float* W_lin1   = (const float*)d_in[9];
    const float* b_lin1   = (const float*)d_in[10];
    float* out = (float*)d_out;
    float* ws  = (float*)d_ws;

    float* sim  = ws + OFF_ADJ;
    float* x1p  = ws + OFF_X1;
    float* nafT = ws + OFF_NAF;
    float* rinv = ws + OFF_RINV;
    float* Wh   = ws + OFF_WH;
    float* f1h  = ws + OFF_F1H;
    float* f2h  = ws + OFF_F2H;
    float* x2   = ws + OFF_X2;
    float* Wh2  = ws + OFF_WH2;
    float* f1s  = ws + OFF_F1S;
    float* f2s  = ws + OFF_F2S;
    float* x3   = ws + OFF_X3;
    float* pmax = ws + OFF_PM2;
    float* psum = ws + OFF_PS2;
    float* fmx  = ws + OFF_FMAX;
    float* fis  = ws + OFF_FIS;
    float* l1   = ws + OFF_L1;
    float* l2   = ws + OFF_L2;
    float* acc1 = ws + OFF_WH2;                               // alias (see layout notes)
    float* acc2 = ws + OFF_X1;                                // alias (zeroed by mh_fin)
    unsigned short* Whbf  = (unsigned short*)(ws + OFF_X2);   // alias: x2 region before mh_fin
    unsigned short* Wh2bf = (unsigned short*)(ws + OFF_X1 + (long)MU * 256);  // alias
    double* parts = (double*)(ws + OFF_PARTS);                // in dead sim rows >= TC
    unsigned long long* posb  = (unsigned long long*)(ws + OFF_POSB);
    unsigned long long* maskT = (unsigned long long*)(ws + OFF_MASKB);

    dim3 b256(256);

    // zero mh partial accumulator + l1/l2 row-sum buffers in one launch
    zero2_k<<<dim3(1172), b256, 0, stream>>>(acc1, (long)NTOT * 64, l1, 5120);
    // x1_pre = x @ W_before + b
    gemm_rm<false, true><<<dim3(72, 4, 1), b256, 0, stream>>>(x, W_before, b_before, x1p, 512, 256, 0, 0);
    // adjacency features: transposed naf, 128-tile sim + fused partials/signs
    af_naf<<<dim3(1152), b256, 0, stream>>>(x1p, W_adj, b_adj, nafT);
    sim_k8<<<dim3(36, 36), b256, 0, stream>>>(nafT, sim, parts, posb);
    // multihead weights
    gemm_rm<true, false><<<dim3(72, 1, 4), b256, 0, stream>>>(x1p, W_heads, nullptr, Wh, 256, 64,
                                                              (long)256 * 64, (long)NTOT * 64);
    // fused: cvt(Wh->bf16) + dots(f1/f2) + rowfin(rinv + transposed masks)
    fused1<<<dim3(288 + 4608 + 1152), b256, 0, stream>>>(Wh, Whbf, a_heads, f1h, f2h,
                                                         parts, posb, rinv, maskT);
    mh_attn<<<dim3(72, 4, 6), b256, 0, stream>>>(maskT, f1h, f2h, Whbf, acc1, l1);
    mh_fin<<<dim3(NTOT * 256 / 1024), b256, 0, stream>>>(acc1, l1, x1p, x2);
    // single GAT (acc2 already zeroed by mh_fin)
    gemm_rm<false, false><<<dim3(72, 4, 1), b256, 0, stream>>>(x2, W_out, nullptr, Wh2, 256, 256, 0, 0);
    fused2<<<dim3(288 + 1152), b256, 0, stream>>>(Wh2, Wh2bf, a_out, f1s, f2s);
    s_attn<<<dim3(48, 2, 12), b256, 0, stream>>>(maskT, f1s, f2s, Wh2bf, acc2, l2);
    s_fin<<<dim3(MU * 256 / 1024), b256, 0, stream>>>(acc2, l2, x2, x3);
    // feat_mlp rows TC.. -> out[0 : 1536*512]
    gemm_rm<false, true><<<dim3(24, 8, 1), b256, 0, stream>>>(x3, W_lin1, b_lin1, out, 256, 512, 0, 0);
    // bi-softmax outputs (16-row chunks: 8x the parallelism of the old 128-row chunks)
    bi_partial<<<dim3(6, 96, 2), b256, 0, stream>>>(sim, rinv, pmax, psum);
    bi_combine<<<dim3(12), b256, 0, stream>>>(pmax, psum, fmx, fis);
    bi_norm<<<dim3(6, 96, 2), b256, 0, stream>>>(sim, rinv, fmx, fis, out + (long)MU * 512);
}

// Round 19
// 342.853 us; speedup vs baseline: 1.0177x; 1.0177x over previous
//
#include <hip/hip_runtime.h>
#include <hip/hip_bf16.h>
#include <math.h>

// Problem constants (from reference)
constexpr int NTOT = 4608;   // N_NODES
constexpr int TC   = 3072;   // TOTAL_CATS
constexpr int MU   = 1536;   // MAX_UNIFY
constexpr int NH   = 4;      // heads

// ---------------- workspace layout (float offsets) ----------------
constexpr long OFF_ADJ  = 0;                                  // N*N sim region (partially used)
constexpr long OFF_X1   = OFF_ADJ  + (long)NTOT*NTOT;         // N*256 (pre-relu)
constexpr long OFF_NAF  = OFF_X1   + (long)NTOT*256;          // naf_T [64][NTOT]
constexpr long OFF_PART = OFF_NAF  + (long)NTOT*64;           // (unused)
constexpr long OFF_RINV = OFF_PART + 72*64;                   // N
constexpr long OFF_WH   = OFF_RINV + NTOT;                    // 4*N*64
constexpr long OFF_F1H  = OFF_WH   + (long)4*NTOT*64;         // 4*N
constexpr long OFF_F2H  = OFF_F1H  + (long)4*NTOT;
constexpr long OFF_MXH  = OFF_F2H  + (long)4*NTOT;            // (unused)
constexpr long OFF_CIH  = OFF_MXH  + (long)4*NTOT;            // (unused)
constexpr long OFF_X2   = OFF_CIH  + (long)4*NTOT;            // N*256
constexpr long OFF_WH2  = OFF_X2   + (long)NTOT*256;          // N*256 (acc1 before Wh2 exists)
constexpr long OFF_F1S  = OFF_WH2  + (long)NTOT*256;          // N
constexpr long OFF_F2S  = OFF_F1S  + NTOT;
constexpr long OFF_MXS  = OFF_F2S  + NTOT;                    // (unused)
constexpr long OFF_CIS  = OFF_MXS  + NTOT;                    // (unused)
constexpr long OFF_X3   = OFF_CIS  + NTOT;                    // 1536*256
constexpr long OFF_PMAX = OFF_X3   + (long)MU*256;            // (unused now; bi partials in scratch)
constexpr long OFF_PSUM = OFF_PMAX + (long)2*12*MU;
constexpr long OFF_FMAX = OFF_PSUM + (long)2*12*MU;           // 2*1536
constexpr long OFF_FIS  = OFF_FMAX + (long)2*MU;
constexpr long OFF_L1   = OFF_FIS  + (long)2*MU;              // 4*N unnormalized row sums (mh)
constexpr long OFF_L2   = OFF_L1   + (long)4*NTOT;            // MU row sums (s)
// sim region: values stored ONLY for rows<TC, cols>=TC. Rows>=TC carved as scratch:
constexpr long OFF_PARTS = OFF_ADJ + (long)TC*NTOT;           // double[NTOT][36] row-sum partials (128-col granule)
constexpr long OFF_POSB  = OFF_PARTS + 2L*NTOT*36;            // u64[NTOT][72] sign words
constexpr long OFF_MASKB = OFF_POSB  + 2L*NTOT*72;            // u64[72][NTOT] mask words (TRANSPOSED)
constexpr long OFF_PM2   = OFF_MASKB + 2L*NTOT*72;            // float[2][96][MU] bi chunk max
constexpr long OFF_PS2   = OFF_PM2   + 2L*96*MU;              // float[2][96][MU] bi chunk sum
// Aliases (lifetime-checked):
//   acc1  = OFF_WH2 region (dead until Wh2 gemm, after mh_fin)
//   Whbf  = OFF_X2 region as bf16 [4][64][NTOT] (x2 written only by mh_fin)
//   acc2  = OFF_X1 (x1p dead after mh_fin; mh_fin itself zeroes it); Wh2bf = OFF_X1 + MU*256 as bf16
// Numerics constraints (rounds 1-5 post-mortems):
//   - rinv MUST be the fp64 sum of the fp32-ROUNDED sim values (exact naf.S fails at 0.154;
//     bf16-MFMA values fail at 0.16-0.40). Full matrix stays fp32 FMA, r0 per-element K-order.
//   - fp64 partial GRANULARITY is free (association at ~1e-16): parts at 128-col granule.
// Perf record (final): r13 attn composite | r14 bi 16-row chunks | r17 = 343.2us BEST.
//   Refuted: sim A-from-global (r15), sim 512-thread (r16, VGPR spill), sim BK=16 (r18,
//   occupancy unchanged -> barriers pure cost). This file = r17 restored; session 394.7->343.2.

typedef __attribute__((ext_vector_type(8))) short bf16x8;
typedef __attribute__((ext_vector_type(8))) unsigned short ushort8;
typedef __attribute__((ext_vector_type(4))) float floatx4;

__device__ __forceinline__ float elu(float x)   { return (x > 0.f) ? x : expm1f(x); }
__device__ __forceinline__ unsigned short f2bf(float f) {
    unsigned u = __float_as_uint(f);
    u += 0x7FFFu + ((u >> 16) & 1u);           // round-to-nearest-even
    return (unsigned short)(u >> 16);
}

// ---------------- zero-fill two regions (float4 units) ----------------
__global__ __launch_bounds__(256) void zero2_k(
    float* __restrict__ a, long na4, float* __restrict__ b, long nb4)
{
    long i = (long)blockIdx.x * 256 + threadIdx.x;
    float4 z = make_float4(0.f, 0.f, 0.f, 0.f);
    if (i < na4) *(float4*)(a + i * 4) = z;
    else {
        long j = i - na4;
        if (j < nb4) *(float4*)(b + j * 4) = z;
    }
}

// ---------------- generic tiled fp32 GEMM: C = A(NxK) @ B(KxM) [+bias] ----------------
template<bool RELU_A, bool BIAS>
__global__ __launch_bounds__(256) void gemm_rm(
    const float* __restrict__ A, const float* __restrict__ B,
    const float* __restrict__ bias, float* __restrict__ C,
    int K, int M, long strideBz, long strideCz)
{
    __shared__ float As[16][68];
    __shared__ float Bs[16][68];
    const float* Bz = B + (long)blockIdx.z * strideBz;
    float* Cz = C + (long)blockIdx.z * strideCz;
    int tid = threadIdx.x;
    int r0 = blockIdx.x * 64;
    int c0 = blockIdx.y * 64;
    int ty = tid >> 4, tx = tid & 15;
    int srow = tid >> 2, skg = tid & 3;     // A staging role
    int bkk = tid >> 4, bc4 = (tid & 15) * 4;  // B staging role (float4)
    const float* Arow = A + (long)(r0 + srow) * K + skg * 4;
    float4 aReg = *(const float4*)(Arow);
    float4 bReg = *(const float4*)&Bz[(long)bkk * M + c0 + bc4];
    float acc[4][4] = {};
    for (int k0 = 0; k0 < K; k0 += 16) {
        {
            float4 v = aReg;
            if (RELU_A) {
                v.x = fmaxf(v.x, 0.f); v.y = fmaxf(v.y, 0.f);
                v.z = fmaxf(v.z, 0.f); v.w = fmaxf(v.w, 0.f);
            }
            As[skg * 4 + 0][srow] = v.x;
            As[skg * 4 + 1][srow] = v.y;
            As[skg * 4 + 2][srow] = v.z;
            As[skg * 4 + 3][srow] = v.w;
            *(float4*)&Bs[bkk][bc4] = bReg;
        }
        __syncthreads();
        if (k0 + 16 < K) {   // prefetch next tile; latency hides under the FMA loop
            aReg = *(const float4*)(Arow + k0 + 16);
            bReg = *(const float4*)&Bz[(long)(k0 + 16 + bkk) * M + c0 + bc4];
        }
        #pragma unroll
        for (int kk = 0; kk < 16; ++kk) {
            float4 av = *(const float4*)&As[kk][ty * 4];
            float4 bv = *(const float4*)&Bs[kk][tx * 4];
            float a[4] = { av.x, av.y, av.z, av.w };
            float b[4] = { bv.x, bv.y, bv.z, bv.w };
            #pragma unroll
            for (int i = 0; i < 4; ++i)
                #pragma unroll
                for (int j = 0; j < 4; ++j) acc[i][j] += a[i] * b[j];
        }
        __syncthreads();
    }
    #pragma unroll
    for (int i = 0; i < 4; ++i) {
        int r = r0 + ty * 4 + i;
        #pragma unroll
        for (int j = 0; j < 4; ++j) {
            int c = c0 + tx * 4 + j;
            float v = acc[i][j];
            if (BIAS) v += bias[c];
            Cz[(long)r * M + c] = v;
        }
    }
}

// ---------------- af = x1 @ W_adj + b_adj; naf_T[k][n] = af/||af|| (transposed) ----------------
__global__ __launch_bounds__(256) void af_naf(
    const float* __restrict__ x1, const float* __restrict__ W_adj,
    const float* __restrict__ b_adj, float* __restrict__ nafT)
{
    __shared__ float rowbuf[4][256];
    int tid = threadIdx.x, w = tid >> 6, lane = tid & 63;
    int n = blockIdx.x * 4 + w;
    #pragma unroll
    for (int l = 0; l < 4; ++l) rowbuf[w][l * 64 + lane] = x1[(long)n * 256 + l * 64 + lane];
    __syncthreads();
    float acc = b_adj[lane];
    for (int k = 0; k < 256; ++k) acc += rowbuf[w][k] * W_adj[k * 64 + lane];
    float sq = acc * acc;
    #pragma unroll
    for (int off = 32; off >= 1; off >>= 1) sq += __shfl_xor(sq, off);
    float nrm = fmaxf(sqrtf(sq), 1e-12f);
    nafT[(long)lane * NTOT + n] = acc / nrm;
}

// ---------------- sim 128x128 tile, 8x8/thread + fused fp64 partials (128-col granule) + signs ----------------
__global__ __launch_bounds__(256) void sim_k8(
    const float* __restrict__ nafT, float* __restrict__ sim,
    double* __restrict__ parts, unsigned long long* __restrict__ posb)
{
    __shared__ float As[32][128];
    __shared__ float Bs[32][128];
    __shared__ unsigned char sgn[128][2][16];
    int tid = threadIdx.x;
    int n0 = blockIdx.x * 128, m0 = blockIdx.y * 128;
    int ty = tid >> 4, tx = tid & 15;
    float acc[2][2][4][4] = {};   // [row-half][col-half][i][j]
    for (int ks = 0; ks < 2; ++ks) {
        if (ks) __syncthreads();
        int k0 = ks * 32;
        #pragma unroll
        for (int l = 0; l < 4; ++l) {
            int idx = l * 256 + tid;
            int kk = idx >> 5, f4 = idx & 31;
            *(float4*)&As[kk][f4 * 4] = *(const float4*)&nafT[(long)(k0 + kk) * NTOT + n0 + f4 * 4];
            *(float4*)&Bs[kk][f4 * 4] = *(const float4*)&nafT[(long)(k0 + kk) * NTOT + m0 + f4 * 4];
        }
        __syncthreads();
        for (int kk = 0; kk < 32; ++kk) {
            float4 av0 = *(const float4*)&As[kk][ty * 4];
            float4 av1 = *(const float4*)&As[kk][64 + ty * 4];
            float4 bv0 = *(const float4*)&Bs[kk][tx * 4];
            float4 bv1 = *(const float4*)&Bs[kk][64 + tx * 4];
            float a[2][4] = { { av0.x, av0.y, av0.z, av0.w }, { av1.x, av1.y, av1.z, av1.w } };
            float b[2][4] = { { bv0.x, bv0.y, bv0.z, bv0.w }, { bv1.x, bv1.y, bv1.z, bv1.w } };
            #pragma unroll
            for (int rh = 0; rh < 2; ++rh)
                #pragma unroll
                for (int ch = 0; ch < 2; ++ch)
                    #pragma unroll
                    for (int i = 0; i < 4; ++i)
                        #pragma unroll
                        for (int j = 0; j < 4; ++j)
                            acc[rh][ch][i][j] += a[rh][i] * b[ch][j];
        }
    }
    // (1) values only for the bi-softmax slice (rows<TC, cols>=TC)
    if (m0 >= TC && n0 < TC) {
        #pragma unroll
        for (int rh = 0; rh < 2; ++rh)
            #pragma unroll
            for (int i = 0; i < 4; ++i) {
                long r = n0 + rh * 64 + ty * 4 + i;
                #pragma unroll
                for (int ch = 0; ch < 2; ++ch) {
                    float4 o = make_float4(acc[rh][ch][i][0], acc[rh][ch][i][1],
                                           acc[rh][ch][i][2], acc[rh][ch][i][3]);
                    *(float4*)(sim + r * NTOT + m0 + ch * 64 + tx * 4) = o;
                }
            }
    }
    // (2) fp64 per-row partial over the FULL 128-col tile (one butterfly per row)
    int mt36 = m0 >> 7;
    #pragma unroll
    for (int rh = 0; rh < 2; ++rh)
        #pragma unroll
        for (int i = 0; i < 4; ++i) {
            double t = 0.0;
            #pragma unroll
            for (int ch = 0; ch < 2; ++ch)
                t += ((double)acc[rh][ch][i][0] + (double)acc[rh][ch][i][1])
                   + ((double)acc[rh][ch][i][2] + (double)acc[rh][ch][i][3]);
            #pragma unroll
            for (int off = 1; off < 16; off <<= 1) t += __shfl_xor(t, off);
            if (tx == 0)
                parts[(long)(n0 + rh * 64 + ty * 4 + i) * 36 + mt36] = t;
        }
    // (3) sign nibbles -> u64 words (bit = local col within 64-col granule)
    int mt = m0 >> 6;
    #pragma unroll
    for (int rh = 0; rh < 2; ++rh)
        #pragma unroll
        for (int i = 0; i < 4; ++i)
            #pragma unroll
            for (int ch = 0; ch < 2; ++ch) {
                unsigned nib = (unsigned)(acc[rh][ch][i][0] > 0.f)
                             | ((unsigned)(acc[rh][ch][i][1] > 0.f) << 1)
                             | ((unsigned)(acc[rh][ch][i][2] > 0.f) << 2)
                             | ((unsigned)(acc[rh][ch][i][3] > 0.f) << 3);
                sgn[rh * 64 + ty * 4 + i][ch][tx] = (unsigned char)nib;
            }
    __syncthreads();
    {
        int rl = tid >> 1, gh = tid & 1;
        unsigned long long w = 0;
        #pragma unroll
        for (int t = 0; t < 16; ++t)
            w |= (unsigned long long)sgn[rl][gh][t] << (4 * t);
        posb[(long)(n0 + rl) * 72 + mt + gh] = w;
    }
}

// ---------------- fused1: cvt_t(Wh heads -> Whbf[4][64][NTOT]) + dots_k(heads) + rowfin ----------------
// maskT layout: maskT[mt * NTOT + n]
__global__ __launch_bounds__(256) void fused1(
    const float* __restrict__ Wh, unsigned short* __restrict__ Whbf,
    const float* __restrict__ a_heads,
    float* __restrict__ f1, float* __restrict__ f2,
    const double* __restrict__ parts, const unsigned long long* __restrict__ posb,
    float* __restrict__ rinv, unsigned long long* __restrict__ maskT)
{
    __shared__ float t[64][65];
    int b = blockIdx.x;
    int tid = threadIdx.x;
    if (b < 288) {
        // cvt_t: in [4][NTOT][64] fp32 -> out [4][64][NTOT] bf16
        int bx = b % 72, bz = b / 72;
        int n0 = bx * 64;
        const float* inz = Wh + (long)bz * NTOT * 64;
        unsigned short* outz = Whbf + (long)bz * 64 * NTOT;
        int r4 = tid >> 6, k = tid & 63;
        #pragma unroll
        for (int l = 0; l < 16; ++l) {
            int row = l * 4 + r4;
            t[row][k] = inz[(long)(n0 + row) * 64 + k];
        }
        __syncthreads();
        #pragma unroll
        for (int l = 0; l < 16; ++l) {
            int drow = l * 4 + r4;
            outz[(long)drow * NTOT + n0 + k] = f2bf(t[k][drow]);
        }
    } else if (b < 288 + 4608) {
        // dots_k heads (D=64)
        int tb = b - 288;
        int xb = tb % 1152, h = tb / 1152;
        int w = tid >> 6, lane = tid & 63;
        int n = xb * 4 + w;
        const float* row = Wh + ((long)h * NTOT + n) * 64;
        const float* a1 = a_heads + (long)h * 128;
        const float* a2 = a1 + 64;
        float v = row[lane];
        float p1 = v * a1[lane];
        float p2 = v * a2[lane];
        #pragma unroll
        for (int off = 32; off >= 1; off >>= 1) { p1 += __shfl_xor(p1, off); p2 += __shfl_xor(p2, off); }
        if (lane == 0) {
            f1[(long)h * NTOT + n] = p1;
            f2[(long)h * NTOT + n] = p2;
        }
    } else {
        // rowfin: combine 36 fp64 partials -> rinv; sign words -> TRANSPOSED mask words
        int xb = b - (288 + 4608);
        int w = tid >> 6, lane = tid & 63;
        int n = xb * 4 + w;
        double s = (lane < 36) ? parts[(long)n * 36 + lane] : 0.0;
        #pragma unroll
        for (int off = 32; off >= 1; off >>= 1) s += __shfl_xor(s, off);
        float rs = (float)s;
        float r = 1.0f / rs;
        if (isinf(r)) r = 0.f;
        if (lane == 0) rinv[n] = r;
        unsigned long long pw = posb[(long)n * 72 + lane];
        unsigned long long mw = (r < 0.f) ? ~pw : pw;
        if (r == 0.f) mw = 0ull;
        maskT[(long)lane * NTOT + n] = mw;
        if (lane < 8) {
            pw = posb[(long)n * 72 + 64 + lane];
            mw = (r < 0.f) ? ~pw : pw;
            if (r == 0.f) mw = 0ull;
            maskT[(long)(64 + lane) * NTOT + n] = mw;
        }
    }
}

// ---------------- fused2: cvt_t(Wh2 -> Wh2bf[256][NTOT]) + dots_k(single, D=256) ----------------
__global__ __launch_bounds__(256) void fused2(
    const float* __restrict__ Wh2, unsigned short* __restrict__ Wh2bf,
    const float* __restrict__ a_out,
    float* __restrict__ f1, float* __restrict__ f2)
{
    __shared__ float t[64][65];
    int b = blockIdx.x;
    int tid = threadIdx.x;
    if (b < 288) {
        int bx = b % 72, by = b / 72;
        int n0 = bx * 64, d0 = by * 64;
        int r4 = tid >> 6, k = tid & 63;
        #pragma unroll
        for (int l = 0; l < 16; ++l) {
            int row = l * 4 + r4;
            t[row][k] = Wh2[(long)(n0 + row) * 256 + d0 + k];
        }
        __syncthreads();
        #pragma unroll
        for (int l = 0; l < 16; ++l) {
            int drow = l * 4 + r4;
            Wh2bf[(long)(d0 + drow) * NTOT + n0 + k] = f2bf(t[k][drow]);
        }
    } else {
        int xb = b - 288;
        int w = tid >> 6, lane = tid & 63;
        int n = xb * 4 + w;
        const float* row = Wh2 + (long)n * 256;
        const float* a1 = a_out;
        const float* a2 = a_out + 256;
        float p1 = 0.f, p2 = 0.f;
        #pragma unroll
        for (int l = 0; l < 4; ++l) {
            float v = row[l * 64 + lane];
            p1 += v * a1[l * 64 + lane];
            p2 += v * a2[l * 64 + lane];
        }
        #pragma unroll
        for (int off = 32; off >= 1; off >>= 1) { p1 += __shfl_xor(p1, off); p2 += __shfl_xor(p2, off); }
        if (lane == 0) {
            f1[n] = p1;
            f2[n] = p2;
        }
    }
}

// ---------------- multihead att @ Wh — LDS stride 72, inline exp, register-pipelined staging ----------------
__global__ __launch_bounds__(256) void mh_attn(
    const unsigned long long* __restrict__ maskT,
    const float* __restrict__ f1, const float* __restrict__ f2,
    const unsigned short* __restrict__ Whbf, float* __restrict__ accb,
    float* __restrict__ lbuf)
{
    __shared__ unsigned short Ws[2][64][72];   // Wh tile transposed [d][m] bf16
    int tid = threadIdx.x;
    int wave = tid >> 6, lane = tid & 63;
    int n0 = blockIdx.x * 64;
    int h = blockIdx.y, ch = blockIdx.z;
    const float* f2h = f2 + (long)h * NTOT;
    const unsigned short* Wb = Whbf + (long)h * 64 * NTOT;
    int wd = tid >> 2, wc = (tid & 3) * 16;
    int arow = lane & 15, acol8 = (lane >> 4) * 8;
    int n = n0 + 16 * wave + arow;
    float r1 = f1[(long)h * NTOT + n];
    float lsum = 0.f;
    floatx4 acc[4] = {};
    int buf = 0;
    int mt0 = ch * 12;
    // preload iteration 0 staging + mask
    ushort8 wv0 = *(const ushort8*)&Wb[(long)wd * NTOT + mt0 * 64 + wc];
    ushort8 wv1 = *(const ushort8*)&Wb[(long)wd * NTOT + mt0 * 64 + wc + 8];
    unsigned long long mw = maskT[(long)mt0 * NTOT + n];
    for (int i = 0; i < 12; ++i) {
        int m0 = (mt0 + i) * 64;
        // P-gen: f2 table loads inline (L1-hot) + inline exp (VALU covers staging latency)
        bf16x8 afr[2];
        #pragma unroll
        for (int ks = 0; ks < 2; ++ks) {
            int mc = m0 + ks * 32 + acol8;
            float4 fv0 = *(const float4*)(f2h + mc);
            float4 fv1 = *(const float4*)(f2h + mc + 4);
            unsigned bits = (unsigned)(mw >> (ks * 32 + acol8)) & 0xFFu;
            float f[8] = { fv0.x, fv0.y, fv0.z, fv0.w, fv1.x, fv1.y, fv1.z, fv1.w };
            #pragma unroll
            for (int j = 0; j < 8; ++j) {
                float s = r1 + f[j];
                float e = __expf(fmaxf(s, 0.2f * s));
                float p = ((bits >> j) & 1u) ? e : 0.f;
                lsum += p;
                afr[ks][j] = (short)f2bf(p);
            }
        }
        *(ushort8*)&Ws[buf][wd][wc] = wv0;
        *(ushort8*)&Ws[buf][wd][wc + 8] = wv1;
        // prefetch iteration i+1 staging + mask (latency hides under barrier + MFMA)
        if (i < 11) {
            int m1 = (mt0 + i + 1) * 64;
            wv0 = *(const ushort8*)&Wb[(long)wd * NTOT + m1 + wc];
            wv1 = *(const ushort8*)&Wb[(long)wd * NTOT + m1 + wc + 8];
            mw = maskT[(long)(mt0 + i + 1) * NTOT + n];
        }
        __syncthreads();
        #pragma unroll
        for (int ks = 0; ks < 2; ++ks) {
            #pragma unroll
            for (int dt = 0; dt < 4; ++dt) {
                bf16x8 bfr = *(bf16x8*)&Ws[buf][16 * dt + arow][ks * 32 + acol8];
                acc[dt] = __builtin_amdgcn_mfma_f32_16x16x32_bf16(afr[ks], bfr, acc[dt], 0, 0, 0);
            }
        }
        buf ^= 1;
    }
    lsum += __shfl_xor(lsum, 16);
    lsum += __shfl_xor(lsum, 32);
    if (lane < 16) atomicAdd(lbuf + (long)h * NTOT + n0 + 16 * wave + lane, lsum);
    int crow = n0 + 16 * wave + (lane >> 4) * 4;
    int ccol = h * 64 + (lane & 15);
    #pragma unroll
    for (int dt = 0; dt < 4; ++dt)
        #pragma unroll
        for (int r = 0; r < 4; ++r)
            atomicAdd(accb + (long)(crow + r) * 256 + ccol + dt * 16, acc[dt][r]);
}

// ---------------- mh epilogue: x2 = elu(acc / l') + relu(x1); also zeroes acc2 region ----------------
__global__ __launch_bounds__(256) void mh_fin(
    const float* __restrict__ accb, const float* __restrict__ lbuf,
    float* __restrict__ x1, float* __restrict__ x2)
{
    long idx = ((long)blockIdx.x * 256 + threadIdx.x) * 4;
    long r = idx >> 8;
    int h = (int)((idx & 255) >> 6);
    float l = lbuf[(long)h * NTOT + r];
    float inv = (l > 0.f) ? 1.0f / l : 0.f;
    float4 a = *(const float4*)(accb + idx);
    float4 xv = *(const float4*)(x1 + idx);
    float4 o;
    o.x = elu(a.x * inv) + fmaxf(xv.x, 0.f);
    o.y = elu(a.y * inv) + fmaxf(xv.y, 0.f);
    o.z = elu(a.z * inv) + fmaxf(xv.z, 0.f);
    o.w = elu(a.w * inv) + fmaxf(xv.w, 0.f);
    *(float4*)(x2 + idx) = o;
    // pre-zero acc2 (aliases head of x1p region, which is dead after this read)
    if (idx < (long)MU * 256)
        *(float4*)(x1 + idx) = make_float4(0.f, 0.f, 0.f, 0.f);
}

// ---------------- single-head att @ Wh2 (rows >= TC) — LDS stride 72, inline exp, pipelined ----------------
__global__ __launch_bounds__(256) void s_attn(
    const unsigned long long* __restrict__ maskT,
    const float* __restrict__ f1, const float* __restrict__ f2,
    const unsigned short* __restrict__ Wh2bf, float* __restrict__ accb,
    float* __restrict__ lbuf)
{
    __shared__ unsigned short Ws[2][128][72];   // 36.9 KB: 128 d-rows x 64 m, dbuf
    int tid = threadIdx.x;
    int wave = tid >> 6, lane = tid & 63;
    int lr0 = blockIdx.x * 32;
    int c0 = blockIdx.y * 128;
    int ch = blockIdx.z;
    int wdl = tid >> 2, wc = (tid & 3) * 16;    // staging role (applied twice for 128 rows)
    int arow = lane & 15, acol8 = (lane >> 4) * 8;
    int rt = wave & 1;
    int dt0 = (wave >> 1) * 4;                   // 4 d-tiles of 16 per wave
    int n = TC + lr0 + 16 * rt + arow;
    float r1 = f1[n];
    float lsum = 0.f;
    floatx4 acc[4] = {};
    int buf = 0;
    int mt0 = ch * 6;
    // preload iteration 0 staging + mask
    ushort8 wva0 = *(const ushort8*)&Wh2bf[(long)(c0 + wdl) * NTOT + mt0 * 64 + wc];
    ushort8 wva1 = *(const ushort8*)&Wh2bf[(long)(c0 + wdl) * NTOT + mt0 * 64 + wc + 8];
    ushort8 wvb0 = *(const ushort8*)&Wh2bf[(long)(c0 + 64 + wdl) * NTOT + mt0 * 64 + wc];
    ushort8 wvb1 = *(const ushort8*)&Wh2bf[(long)(c0 + 64 + wdl) * NTOT + mt0 * 64 + wc + 8];
    unsigned long long mw = maskT[(long)mt0 * NTOT + n];
    for (int i = 0; i < 6; ++i) {
        int m0 = (mt0 + i) * 64;
        bf16x8 afr[2];
        #pragma unroll
        for (int ks = 0; ks < 2; ++ks) {
            int mc = m0 + ks * 32 + acol8;
            float4 fv0 = *(const float4*)(f2 + mc);
            float4 fv1 = *(const float4*)(f2 + mc + 4);
            unsigned bits = (unsigned)(mw >> (ks * 32 + acol8)) & 0xFFu;
            float f[8] = { fv0.x, fv0.y, fv0.z, fv0.w, fv1.x, fv1.y, fv1.z, fv1.w };
            #pragma unroll
            for (int j = 0; j < 8; ++j) {
                float s = r1 + f[j];
                float e = __expf(fmaxf(s, 0.2f * s));
                float p = ((bits >> j) & 1u) ? e : 0.f;
                lsum += p;
                afr[ks][j] = (short)f2bf(p);
            }
        }
        *(ushort8*)&Ws[buf][wdl][wc] = wva0;
        *(ushort8*)&Ws[buf][wdl][wc + 8] = wva1;
        *(ushort8*)&Ws[buf][64 + wdl][wc] = wvb0;
        *(ushort8*)&Ws[buf][64 + wdl][wc + 8] = wvb1;
        if (i < 5) {
            int m1 = (mt0 + i + 1) * 64;
            wva0 = *(const ushort8*)&Wh2bf[(long)(c0 + wdl) * NTOT + m1 + wc];
            wva1 = *(const ushort8*)&Wh2bf[(long)(c0 + wdl) * NTOT + m1 + wc + 8];
            wvb0 = *(const ushort8*)&Wh2bf[(long)(c0 + 64 + wdl) * NTOT + m1 + wc];
            wvb1 = *(const ushort8*)&Wh2bf[(long)(c0 + 64 + wdl) * NTOT + m1 + wc + 8];
            mw = maskT[(long)(mt0 + i + 1) * NTOT + n];
        }
        __syncthreads();
        #pragma unroll
        for (int ks = 0; ks < 2; ++ks) {
            #pragma unroll
            for (int t = 0; t < 4; ++t) {
                bf16x8 bfr = *(bf16x8*)&Ws[buf][(dt0 + t) * 16 + arow][ks * 32 + acol8];
                acc[t] = __builtin_amdgcn_mfma_f32_16x16x32_bf16(afr[ks], bfr, acc[t], 0, 0, 0);
            }
        }
        buf ^= 1;
    }
    // per-row l': contribute once (col-half 0, waves 0,1 only)
    lsum += __shfl_xor(lsum, 16);
    lsum += __shfl_xor(lsum, 32);
    if (blockIdx.y == 0 && wave < 2 && lane < 16)
        atomicAdd(lbuf + lr0 + 16 * wave + lane, lsum);
    int crow = lr0 + 16 * rt + (lane >> 4) * 4;
    #pragma unroll
    for (int t = 0; t < 4; ++t) {
        int ccol = c0 + (dt0 + t) * 16 + (lane & 15);
        #pragma unroll
        for (int r = 0; r < 4; ++r)
            atomicAdd(accb + (long)(crow + r) * 256 + ccol, acc[t][r]);
    }
}

// ---------------- s epilogue: x3 = elu(acc / l' + x2[TC..]) ----------------
__global__ __launch_bounds__(256) void s_fin(
    const float* __restrict__ accb, const float* __restrict__ lbuf,
    const float* __restrict__ x2, float* __restrict__ x3)
{
    long idx = ((long)blockIdx.x * 256 + threadIdx.x) * 4;
    long r = idx >> 8;
    float l = lbuf[r];
    float inv = (l > 0.f) ? 1.0f / l : 0.f;
    float4 a = *(const float4*)(accb + idx);
    float4 xv = *(const float4*)(x2 + (long)TC * 256 + idx);
    float4 o;
    o.x = elu(a.x * inv + xv.x);
    o.y = elu(a.y * inv + xv.y);
    o.z = elu(a.z * inv + xv.z);
    o.w = elu(a.w * inv + xv.w);
    *(float4*)(x3 + idx) = o;
}

// ---------------- bi-softmax phase A: 16-row chunks (96 per dataset) ----------------
__global__ __launch_bounds__(256) void bi_partial(
    const float* __restrict__ sim, const float* __restrict__ rinv,
    float* __restrict__ pmax, float* __restrict__ psum)
{
    int c = blockIdx.x * 256 + threadIdx.x;
    int ch = blockIdx.y;                       // 0..95
    int ds = blockIdx.z;
    float m = -3.0e38f, s = 0.f;
    int rbase = ds * MU + ch * 16;
    for (int r = 0; r < 16; ++r) {
        float a = sim[(long)(rbase + r) * NTOT + TC + c] * rinv[rbase + r];
        float v = a * 20.0f;
        if (v <= m) s += expf(v - m);
        else { s = s * expf(m - v) + 1.f; m = v; }
    }
    pmax[((long)ds * 96 + ch) * MU + c] = m;
    psum[((long)ds * 96 + ch) * MU + c] = s;
}

// ---------------- bi-softmax phase B: fold 96 chunk partials ----------------
__global__ __launch_bounds__(256) void bi_combine(
    const float* __restrict__ pmax, const float* __restrict__ psum,
    float* __restrict__ fmax, float* __restrict__ fis)
{
    int b = blockIdx.x;
    int ds = b / 6, ct = b % 6;
    int c = ct * 256 + threadIdx.x;
    float m = -3.0e38f;
    for (int ch = 0; ch < 96; ++ch) m = fmaxf(m, pmax[((long)ds * 96 + ch) * MU + c]);
    float s = 0.f;
    for (int ch = 0; ch < 96; ++ch)
        s += psum[((long)ds * 96 + ch) * MU + c] * expf(pmax[((long)ds * 96 + ch) * MU + c] - m);
    fmax[ds * MU + c] = m;
    fis[ds * MU + c] = 1.0f / s;
}

// ---------------- bi-softmax phase C: 16-row chunks ----------------
__global__ __launch_bounds__(256) void bi_norm(
    const float* __restrict__ sim, const float* __restrict__ rinv,
    const float* __restrict__ fmax, const float* __restrict__ fis,
    float* __restrict__ outbg)
{
    int c = blockIdx.x * 256 + threadIdx.x;
    int ch = blockIdx.y;                       // 0..95
    int ds = blockIdx.z;
    float m = fmax[ds * MU + c], inv = fis[ds * MU + c];
    long obase = (long)ds * MU * MU;
    int rbase = ch * 16;
    for (int r = 0; r < 16; ++r) {
        int row = ds * MU + rbase + r;
        float a = sim[(long)row * NTOT + TC + c] * rinv[row];
        float v = a * 20.0f;
        outbg[obase + (long)(rbase + r) * MU + c] = expf(v - m) * inv;
    }
}

// ---------------- launch ----------------
extern "C" void kernel_launch(void* const* d_in, const int* in_sizes, int n_in,
                              void* d_out, int out_size, void* d_ws, size_t ws_size,
                              hipStream_t stream)
{
    const float* x        = (const float*)d_in[0];
    const float* W_before = (const float*)d_in[1];
    const float* b_before = (const float*)d_in[2];
    const float* W_adj    = (const float*)d_in[3];
    const float* b_adj    = (const float*)d_in[4];
    const float* W_heads  = (const float*)d_in[5];
    const float* a_heads  = (const float*)d_in[6];
    const float* W_out    = (const float*)d_in[7];
    const float* a_out    = (const float*)d_in[8];
    const float* W_lin1   = (const float*)d_in[9];
    const float* b_lin1   = (const float*)d_in[10];
    float* out = (float*)d_out;
    float* ws  = (float*)d_ws;

    float* sim  = ws + OFF_ADJ;
    float* x1p  = ws + OFF_X1;
    float* nafT = ws + OFF_NAF;
    float* rinv = ws + OFF_RINV;
    float* Wh   = ws + OFF_WH;
    float* f1h  = ws + OFF_F1H;
    float* f2h  = ws + OFF_F2H;
    float* x2   = ws + OFF_X2;
    float* Wh2  = ws + OFF_WH2;
    float* f1s  = ws + OFF_F1S;
    float* f2s  = ws + OFF_F2S;
    float* x3   = ws + OFF_X3;
    float* pmax = ws + OFF_PM2;
    float* psum = ws + OFF_PS2;
    float* fmx  = ws + OFF_FMAX;
    float* fis  = ws + OFF_FIS;
    float* l1   = ws + OFF_L1;
    float* l2   = ws + OFF_L2;
    float* acc1 = ws + OFF_WH2;                               // alias (see layout notes)
    float* acc2 = ws + OFF_X1;                                // alias (zeroed by mh_fin)
    unsigned short* Whbf  = (unsigned short*)(ws + OFF_X2);   // alias: x2 region before mh_fin
    unsigned short* Wh2bf = (unsigned short*)(ws + OFF_X1 + (long)MU * 256);  // alias
    double* parts = (double*)(ws + OFF_PARTS);                // in dead sim rows >= TC
    unsigned long long* posb  = (unsigned long long*)(ws + OFF_POSB);
    unsigned long long* maskT = (unsigned long long*)(ws + OFF_MASKB);

    dim3 b256(256);

    // zero mh partial accumulator + l1/l2 row-sum buffers in one launch
    zero2_k<<<dim3(1172), b256, 0, stream>>>(acc1, (long)NTOT * 64, l1, 5120);
    // x1_pre = x @ W_before + b
    gemm_rm<false, true><<<dim3(72, 4, 1), b256, 0, stream>>>(x, W_before, b_before, x1p, 512, 256, 0, 0);
    // adjacency features: transposed naf, 128-tile sim + fused partials/signs
    af_naf<<<dim3(1152), b256, 0, stream>>>(x1p, W_adj, b_adj, nafT);
    sim_k8<<<dim3(36, 36), b256, 0, stream>>>(nafT, sim, parts, posb);
    // multihead weights
    gemm_rm<true, false><<<dim3(72, 1, 4), b256, 0, stream>>>(x1p, W_heads, nullptr, Wh, 256, 64,
                                                              (long)256 * 64, (long)NTOT * 64);
    // fused: cvt(Wh->bf16) + dots(f1/f2) + rowfin(rinv + transposed masks)
    fused1<<<dim3(288 + 4608 + 1152), b256, 0, stream>>>(Wh, Whbf, a_heads, f1h, f2h,
                                                         parts, posb, rinv, maskT);
    mh_attn<<<dim3(72, 4, 6), b256, 0, stream>>>(maskT, f1h, f2h, Whbf, acc1, l1);
    mh_fin<<<dim3(NTOT * 256 / 1024), b256, 0, stream>>>(acc1, l1, x1p, x2);
    // single GAT (acc2 already zeroed by mh_fin)
    gemm_rm<false, false><<<dim3(72, 4, 1), b256, 0, stream>>>(x2, W_out, nullptr, Wh2, 256, 256, 0, 0);
    fused2<<<dim3(288 + 1152), b256, 0, stream>>>(Wh2, Wh2bf, a_out, f1s, f2s);
    s_attn<<<dim3(48, 2, 12), b256, 0, stream>>>(maskT, f1s, f2s, Wh2bf, acc2, l2);
    s_fin<<<dim3(MU * 256 / 1024), b256, 0, stream>>>(acc2, l2, x2, x3);
    // feat_mlp rows TC.. -> out[0 : 1536*512]
    gemm_rm<false, true><<<dim3(24, 8, 1), b256, 0, stream>>>(x3, W_lin1, b_lin1, out, 256, 512, 0, 0);
    // bi-softmax outputs (16-row chunks: 8x the parallelism of the old 128-row chunks)
    bi_partial<<<dim3(6, 96, 2), b256, 0, stream>>>(sim, rinv, pmax, psum);
    bi_combine<<<dim3(12), b256, 0, stream>>>(pmax, psum, fmx, fis);
    bi_norm<<<dim3(6, 96, 2), b256, 0, stream>>>(sim, rinv, fmx, fis, out + (long)MU * 512);
}